// Round 7
// baseline (226.342 us; speedup 1.0000x reference)
//
#include <hip/hip_runtime.h>
#include <hip/hip_bf16.h>
#include <math.h>

// Problem constants (B=2, C=256, H=W=64, Co=256, 3x3, stride1, pad1)
#define BB 2
#define CC 256
#define HH 64
#define WW 64
#define COo 256
#define HWs 4096
#define K2 9
#define CK 2304   // C*9

typedef __attribute__((ext_vector_type(4))) float floatx4;
typedef __attribute__((ext_vector_type(8))) short shortx8;   // 8 bf16 = 4 VGPRs

// ---- workspace layout (float units) ----
#define O_OFF   0          // final offset  B*18*4096 = 147456 f
#define O_MASK  147456     // final modulator B*9*4096 = 73728 f
#define O_WBF   221184     // reg_w bf16 [co][ck] = 294912 f
#define O_WPK   516096     // convA weights [g2][kc8][tap9][nf2][lane][8] = 73728 f
#define O_A     589824     // A matrix bf16 [pix 8192][ck 2304] = 9437184 f
#define O_XT    10027008   // x NHWC bf16 [b][y][x][c] = 2*4096*256 bf16 = 1048576 f
// P (convA fp16 partials, [kc8][b2][pix4096][27]) aliases the head of O_A
// (dead after reduce_kernel, before gather writes A).
// total = 11,075,584 floats = 44.3 MB

__device__ __forceinline__ void gll16(const __hip_bfloat16* g, __hip_bfloat16* l) {
    __builtin_amdgcn_global_load_lds(
        (const __attribute__((address_space(1))) unsigned int*)g,
        (__attribute__((address_space(3))) unsigned int*)l, 16, 0, 0);
}

__device__ __forceinline__ short f2bf(float v) {
    __hip_bfloat16 h = __float2bfloat16(v);
    return *reinterpret_cast<short*>(&h);
}

__device__ __forceinline__ float bf2f(short s) {
    unsigned u = ((unsigned)(unsigned short)s) << 16;
    return __builtin_bit_cast(float, u);
}

// ---------------------------------------------------------------------------
// K0: pack weights (unchanged from R6).
// ---------------------------------------------------------------------------
__global__ __launch_bounds__(256) void pack_kernel(
    const float* __restrict__ reg_w,
    const float* __restrict__ off_w,
    const float* __restrict__ mod_w,
    __hip_bfloat16* __restrict__ Wbf,
    __hip_bfloat16* __restrict__ Wpk)
{
    int idx = blockIdx.x * 256 + threadIdx.x;
    if (idx < CK * COo) {
        Wbf[idx] = __float2bfloat16(reg_w[idx]);
    }
    if (idx < 147456) {
        int g    = idx / 73728;
        int rem  = idx % 73728;
        int kc   = rem / 9216;
        int r2   = rem % 9216;
        int tap  = r2 / 1024;
        int r3   = r2 & 1023;
        int nf   = r3 >> 9;
        int r4   = r3 & 511;
        int lane = r4 >> 3;
        int j    = r4 & 7;
        int c    = kc * 32 + (lane >> 4) * 8 + j;
        int n    = nf * 16 + (lane & 15);
        float v = 0.f;
        if (g == 0) { if (n < 18) v = off_w[((size_t)n * CC + c) * 9 + tap]; }
        else        { if (n < 9)  v = mod_w[((size_t)n * CC + c) * 9 + tap]; }
        Wpk[idx] = __float2bfloat16(v);
    }
}

// ---------------------------------------------------------------------------
// K0b: x (NCHW fp32) -> xT (NHWC bf16). grid = B*H*8, block 256.
// Thread: 8 strided channel loads (lane-coalesced), one 16B c-contiguous store.
// ---------------------------------------------------------------------------
__global__ __launch_bounds__(256) void transpose_kernel(
    const float* __restrict__ x,
    __hip_bfloat16* __restrict__ xT)
{
    int blk = blockIdx.x;            // ((b*64 + y)*8 + oc)
    int oc = blk & 7;
    int y  = (blk >> 3) & 63;
    int b  = blk >> 9;
    int t = threadIdx.x;
    int wo = t & 63;
    int cg = t >> 6;
    int c0 = oc * 32 + cg * 8;
    const float* src = x + ((size_t)(b * CC + c0) * HH + y) * WW + wo;
    shortx8 pk;
#pragma unroll
    for (int j = 0; j < 8; ++j) pk[j] = f2bf(src[(size_t)j * HWs]);
    *(shortx8*)(xT + ((size_t)b * 4096 + y * 64 + wo) * 256 + c0) = pk;
}

// ---------------------------------------------------------------------------
// K1: offset + modulator convs via MFMA. grid 256 = (b2,g2,kc8,rt8).
// Xs in CHANNEL-MAJOR layout [chunk4][colIdx 640][8]: 4-word lane stride ->
// even bank cover, conflict-free writes AND reads (R6 row-major was ~16-way).
// ---------------------------------------------------------------------------
__global__ __launch_bounds__(256) void convA_kernel(
    const float* __restrict__ x,
    const float* __restrict__ residual,
    const __hip_bfloat16* __restrict__ Wpk,
    _Float16* __restrict__ P)
{
    int blk = blockIdx.x;
    int rt = blk & 7;
    int kc = (blk >> 3) & 7;
    int g  = (blk >> 6) & 1;
    int b  = blk >> 7;
    int t = threadIdx.x;
    int lane = t & 63;
    int w = t >> 6;
    int ln = lane & 15;
    int quad = lane >> 4;

    __shared__ __hip_bfloat16 Xs[4 * 640 * 8];   // [chunk][row*64+col][8] (40 KB)
    __shared__ __hip_bfloat16 Wl[9216];          // weight slice (18 KB)

    const float* src = (g ? x : residual) + ((size_t)b * CC + kc * 32) * HWs;
    const __hip_bfloat16* wsrc = Wpk + (size_t)(g * 8 + kc) * 9216;

    // weight staging: 1152 16B chunks via global_load_lds
#pragma unroll
    for (int i = 0; i < 4; ++i) {
        int cid = i * 256 + t;
        gll16(wsrc + cid * 8, &Wl[cid * 8]);
    }
    if (t < 128) {
        int cid = 1024 + t;
        gll16(wsrc + cid * 8, &Wl[cid * 8]);
    }

    // x-tile staging: rows rt*8-1 .. rt*8+8 (zero-padded), channel-major
    int col = t & 63;
    int q = t >> 6;
#pragma unroll
    for (int i = 0; i < 10; ++i) {
        int p = q * 10 + i;            // 0..39
        int row = p >> 2;              // 0..9
        int cgp = p & 3;               // c-chunk of 8
        int rimg = rt * 8 + row - 1;
        bool rv = (rimg >= 0) && (rimg < HH);
        const float* sp = src + (size_t)(cgp * 8) * HWs + rimg * WW + col;
        shortx8 pk;
#pragma unroll
        for (int jc = 0; jc < 8; ++jc)
            pk[jc] = f2bf(rv ? sp[(size_t)jc * HWs] : 0.f);
        *(shortx8*)&Xs[(cgp * 640 + row * 64 + col) * 8] = pk;
    }
    __syncthreads();                   // drains ds_writes + weight DMA

    floatx4 acc[8][2];
#pragma unroll
    for (int mf = 0; mf < 8; ++mf) {
        acc[mf][0] = (floatx4){0.f, 0.f, 0.f, 0.f};
        acc[mf][1] = (floatx4){0.f, 0.f, 0.f, 0.f};
    }

#pragma unroll
    for (int tap = 0; tap < 9; ++tap) {
        int ky = tap / 3;
        int kx = tap % 3;
        const __hip_bfloat16* wp = &Wl[((tap * 2) * 64 + lane) * 8];
        shortx8 b0 = *(const shortx8*)wp;
        shortx8 b1 = *(const shortx8*)(wp + 512);
#pragma unroll
        for (int mf = 0; mf < 8; ++mf) {
            int p = (w * 8 + mf) * 16 + ln;
            int row_local = p >> 6;
            int colp = p & 63;
            int colA = colp + kx - 1;
            bool cv = (colA >= 0) && (colA < WW);
            int colC = cv ? colA : 0;
            shortx8 afr = *(const shortx8*)
                &Xs[(quad * 640 + (row_local + ky) * 64 + colC) * 8];
            if (!cv) {
                shortx8 zf = {0,0,0,0,0,0,0,0};
                afr = zf;
            }
            acc[mf][0] = __builtin_amdgcn_mfma_f32_16x16x32_bf16(afr, b0, acc[mf][0], 0, 0, 0);
            acc[mf][1] = __builtin_amdgcn_mfma_f32_16x16x32_bf16(afr, b1, acc[mf][1], 0, 0, 0);
        }
    }

    // epilogue: C/D col=lane&15 (=n), row=quad*4+reg (=pixel within frag)
#pragma unroll
    for (int nf = 0; nf < 2; ++nf) {
        int n = nf * 16 + ln;
        bool valid = g ? (n < 9) : (n < 18);
        int n_eff = g ? (18 + n) : n;
        if (valid) {
#pragma unroll
            for (int mf = 0; mf < 8; ++mf) {
#pragma unroll
                for (int i2 = 0; i2 < 4; ++i2) {
                    int p = (w * 8 + mf) * 16 + quad * 4 + i2;
                    int pix = rt * 512 + p;
                    P[((size_t)(kc * 2 + b) * 4096 + pix) * 27 + n_eff] =
                        (_Float16)acc[mf][nf][i2];
                }
            }
        }
    }
}

// ---------------------------------------------------------------------------
// K1b: reduce 8 kc-partials + bias (+2*sigmoid) -> final off/mask. grid 864.
// ---------------------------------------------------------------------------
__global__ __launch_bounds__(256) void reduce_kernel(
    const _Float16* __restrict__ P,
    const float* __restrict__ off_b,
    const float* __restrict__ mod_b,
    float* __restrict__ off_out,
    float* __restrict__ mask_out)
{
    int id = blockIdx.x * 256 + threadIdx.x;
    if (id >= 2 * 4096 * 27) return;
    int n = id % 27;
    int pb = id / 27;
    int pix = pb & 4095;
    int b = pb >> 12;
    float s = 0.f;
#pragma unroll
    for (int kcc = 0; kcc < 8; ++kcc)
        s += (float)P[((size_t)(kcc * 2 + b) * 4096 + pix) * 27 + n];
    if (n < 18) {
        off_out[((size_t)b * 18 + n) * 4096 + pix] = s + off_b[n];
    } else {
        float z = s + mod_b[n - 18];
        mask_out[((size_t)b * 9 + (n - 18)) * 4096 + pix] = 2.f / (1.f + __expf(-z));
    }
}

// ---------------------------------------------------------------------------
// K2: deformable gather -> bf16 A [pix][ck]. grid = B*H*8 (cc of 32 ch);
// block 256 = (wo 64) x (cg 4), 8 channels/thread. Corner loads are 16B
// vectors from xT (NHWC bf16); thread's 72 outputs are contiguous in A ->
// direct 16B-aligned stores, NO LDS transpose.
// ---------------------------------------------------------------------------
__global__ __launch_bounds__(256) void gather_kernel(
    const __hip_bfloat16* __restrict__ xT,
    const float* __restrict__ off,
    const float* __restrict__ mask,
    __hip_bfloat16* __restrict__ A)
{
    int blk = blockIdx.x;            // ((b*64 + ho)*8 + cc)
    int cc = blk & 7;
    int ho = (blk >> 3) & 63;
    int b  = blk >> 9;
    int t  = threadIdx.x;
    int wo = t & 63;
    int cg = t >> 6;

    __shared__ int   s_idx[4][K2][64];
    __shared__ float s_w  [4][K2][64];

    // ---- bilinear precompute from final offset/mask ----
    for (int u = t; u < K2 * 64; u += 256) {
        int k = u >> 6;
        int wv = u & 63;
        float dy = off[((((size_t)b * 18 + 2 * k    ) * HH + ho) << 6) + wv];
        float dx = off[((((size_t)b * 18 + 2 * k + 1) * HH + ho) << 6) + wv];
        float m  = mask[((((size_t)b * 9 + k) * HH + ho) << 6) + wv];
        float py = (float)(ho - 1 + k / 3) + dy;
        float px = (float)(wv - 1 + k % 3) + dx;
        float y0f = floorf(py), x0f = floorf(px);
        float wy1 = py - y0f, wx1 = px - x0f;
        float wy0 = 1.f - wy1, wx0 = 1.f - wx1;
        int y0 = (int)y0f, x0 = (int)x0f;
#pragma unroll
        for (int j = 0; j < 4; ++j) {
            int yy = y0 + (j >> 1);
            int xx = x0 + (j & 1);
            float wj = ((j == 0) ? wy0 * wx0 :
                        (j == 1) ? wy0 * wx1 :
                        (j == 2) ? wy1 * wx0 : wy1 * wx1) * m;
            bool valid = (yy >= 0) && (yy < HH) && (xx >= 0) && (xx < WW);
            s_idx[j][k][wv] = valid ? (yy * WW + xx) : 0;
            s_w  [j][k][wv] = valid ? wj : 0.f;
        }
    }
    __syncthreads();

    const __hip_bfloat16* xb = xT + (size_t)b * 4096 * 256 + cc * 32 + cg * 8;

    shortx8 outv[9];
#pragma unroll
    for (int k = 0; k < K2; ++k) {
        int   i0 = s_idx[0][k][wo], i1 = s_idx[1][k][wo];
        int   i2 = s_idx[2][k][wo], i3 = s_idx[3][k][wo];
        float w0 = s_w[0][k][wo], w1 = s_w[1][k][wo];
        float w2 = s_w[2][k][wo], w3 = s_w[3][k][wo];
        shortx8 c0 = *(const shortx8*)(xb + (size_t)i0 * 256);
        shortx8 c1 = *(const shortx8*)(xb + (size_t)i1 * 256);
        shortx8 c2 = *(const shortx8*)(xb + (size_t)i2 * 256);
        shortx8 c3 = *(const shortx8*)(xb + (size_t)i3 * 256);
#pragma unroll
        for (int j = 0; j < 8; ++j) {
            float v = w0 * bf2f(c0[j]) + w1 * bf2f(c1[j])
                    + w2 * bf2f(c2[j]) + w3 * bf2f(c3[j]);
            int idx = j * 9 + k;       // ck_local within thread's 72-run
            outv[idx >> 3][idx & 7] = f2bf(v);
        }
    }

    __hip_bfloat16* arow = A + (size_t)((b * 64 + ho) * 64 + wo) * CK
                             + cc * 288 + cg * 72;
#pragma unroll
    for (int m = 0; m < 9; ++m)
        *(shortx8*)(arow + m * 8) = outv[m];
}

// ---------------------------------------------------------------------------
// K3: bf16 MFMA GEMM, K-split x2 with deterministic atomic epilogue.
// grid = 256: (mt 128 x ks 2). Tile 64M x 256N x 1152K, BK=32, dbuf DMA.
// XOR chunk placement swz = s ^ (((r&3)+(r>>2))&3) -> 2-way (free) b128 reads.
// Wave w owns co [w*64, w*64+64): acc[4 mf][4 nf].
// ---------------------------------------------------------------------------
__global__ __launch_bounds__(256) void gemm_kernel(
    const __hip_bfloat16* __restrict__ A,
    const __hip_bfloat16* __restrict__ Wbf,
    float* __restrict__ out)
{
    int blk = blockIdx.x;
    int ks = blk & 1;
    int mt = blk >> 1;              // 0..127
    int t  = threadIdx.x;
    int lane = t & 63;
    int w    = t >> 6;
    int quad = lane >> 4;
    int ln   = lane & 15;

    __shared__ __hip_bfloat16 As[2][64 * 32];    // 2 x 4 KB
    __shared__ __hip_bfloat16 Bs[2][256 * 32];   // 2 x 16 KB
    __shared__ float s_out[4][16 * 68];          // per-wave epilogue transpose

    int lr  = lane >> 2;                         // staging row within wave's 16
    int sub = lane & 3;
    int swz = sub ^ (((lr & 3) + ((lr >> 2) & 3)) & 3);
    size_t kbase = (size_t)ks * 1152;
    const __hip_bfloat16* gA = A   + (size_t)(mt * 64 + w * 16 + lr) * CK + kbase + swz * 8;
    const __hip_bfloat16* gB = Wbf + (size_t)(w * 16 + lr) * CK + kbase + swz * 8;
    int lofA = (w * 16) * 32;
    int lofB = (w * 16) * 32;

    floatx4 acc[4][4];
#pragma unroll
    for (int mf = 0; mf < 4; ++mf)
#pragma unroll
        for (int nf = 0; nf < 4; ++nf) acc[mf][nf] = (floatx4){0.f, 0.f, 0.f, 0.f};

    int slot = (quad ^ (((ln & 3) + ((ln >> 2) & 3)) & 3)) * 8;  // read sub-slot

    // prologue: buffer 0
    gll16(gA, &As[0][lofA]);
#pragma unroll
    for (int i = 0; i < 4; ++i)
        gll16(gB + (size_t)(64 * i) * CK, &Bs[0][lofB + i * 64 * 32]);

    for (int kt = 0; kt < 36; ++kt) {
        int cur = kt & 1;
        int nxt = cur ^ 1;
        __syncthreads();
        if (kt + 1 < 36) {
            int ko = (kt + 1) * 32;
            gll16(gA + ko, &As[nxt][lofA]);
#pragma unroll
            for (int i = 0; i < 4; ++i)
                gll16(gB + (size_t)(64 * i) * CK + ko, &Bs[nxt][lofB + i * 64 * 32]);
        }
        shortx8 af[4], bfr[4];
#pragma unroll
        for (int mf = 0; mf < 4; ++mf)
            af[mf] = *(const shortx8*)&As[cur][(mf * 16 + ln) * 32 + slot];
#pragma unroll
        for (int nf = 0; nf < 4; ++nf)
            bfr[nf] = *(const shortx8*)&Bs[cur][(w * 64 + nf * 16 + ln) * 32 + slot];
#pragma unroll
        for (int mf = 0; mf < 4; ++mf)
#pragma unroll
            for (int nf = 0; nf < 4; ++nf)
                acc[mf][nf] = __builtin_amdgcn_mfma_f32_16x16x32_bf16(
                    af[mf], bfr[nf], acc[mf][nf], 0, 0, 0);
    }

    // ---- epilogue: per-wave LDS transpose, coalesced atomicAdd (2 addends
    // from 0 => deterministic) ----
    int bb = mt >> 6;
    int hwbase = (mt & 63) * 64;
    float* sw = &s_out[w][0];
#pragma unroll
    for (int nf = 0; nf < 4; ++nf) {
        __syncthreads();
#pragma unroll
        for (int mf = 0; mf < 4; ++mf)
            *(floatx4*)&sw[ln * 68 + mf * 16 + quad * 4] = acc[mf][nf];
        __syncthreads();
        int co_l = lane >> 2;       // 0..15
        int mq   = lane & 3;
        int co = w * 64 + nf * 16 + co_l;
        float* orow = out + ((size_t)(bb * COo + co) << 12) + hwbase;
#pragma unroll
        for (int c4 = 0; c4 < 4; ++c4) {
            int px = (mq + c4 * 4) * 4;
            floatx4 v = *(const floatx4*)&sw[co_l * 68 + px];
            atomicAdd(&orow[px + 0], v[0]);
            atomicAdd(&orow[px + 1], v[1]);
            atomicAdd(&orow[px + 2], v[2]);
            atomicAdd(&orow[px + 3], v[3]);
        }
    }
}

// ---------------------------------------------------------------------------
extern "C" void kernel_launch(void* const* d_in, const int* in_sizes, int n_in,
                              void* d_out, int out_size, void* d_ws, size_t ws_size,
                              hipStream_t stream)
{
    const float* x     = (const float*)d_in[0];
    const float* resid = (const float*)d_in[1];
    const float* off_w = (const float*)d_in[2];
    const float* off_b = (const float*)d_in[3];
    const float* mod_w = (const float*)d_in[4];
    const float* mod_b = (const float*)d_in[5];
    const float* reg_w = (const float*)d_in[6];
    float* out = (float*)d_out;

    float* ws = (float*)d_ws;
    float* off_buf   = ws + O_OFF;
    float* mask_buf  = ws + O_MASK;
    __hip_bfloat16* Wbf  = (__hip_bfloat16*)(ws + O_WBF);
    __hip_bfloat16* Wpk  = (__hip_bfloat16*)(ws + O_WPK);
    __hip_bfloat16* Abuf = (__hip_bfloat16*)(ws + O_A);
    __hip_bfloat16* xT   = (__hip_bfloat16*)(ws + O_XT);
    _Float16* Pbuf       = (_Float16*)(ws + O_A);   // aliases A head (dead before gather)

    // out must be zero for the K-split atomic epilogue
    hipMemsetAsync(out, 0, (size_t)out_size * sizeof(float), stream);

    pack_kernel<<<(CK * COo + 255) / 256, 256, 0, stream>>>(reg_w, off_w, mod_w, Wbf, Wpk);

    transpose_kernel<<<BB * HH * 8, 256, 0, stream>>>(x, xT);

    convA_kernel<<<256, 256, 0, stream>>>(x, resid, Wpk, Pbuf);

    reduce_kernel<<<864, 256, 0, stream>>>(Pbuf, off_b, mod_b, off_buf, mask_buf);

    gather_kernel<<<BB * HH * 8, 256, 0, stream>>>(xT, off_buf, mask_buf, Abuf);

    gemm_kernel<<<256, 256, 0, stream>>>(Abuf, Wbf, out);
}

// Round 8
// 176.956 us; speedup vs baseline: 1.2791x; 1.2791x over previous
//
#include <hip/hip_runtime.h>
#include <hip/hip_bf16.h>
#include <math.h>

// Problem constants (B=2, C=256, H=W=64, Co=256, 3x3, stride1, pad1)
#define BB 2
#define CC 256
#define HH 64
#define WW 64
#define COo 256
#define HWs 4096
#define K2 9
#define CK 2304   // C*9

typedef __attribute__((ext_vector_type(4))) float floatx4;
typedef __attribute__((ext_vector_type(8))) short shortx8;   // 8 bf16 = 4 VGPRs

// ---- workspace layout (float units) ----
#define O_OFF   0          // final offset  B*18*4096 = 147456 f
#define O_MASK  147456     // final modulator B*9*4096 = 73728 f
#define O_WBF   221184     // reg_w bf16 [co][ck] = 294912 f
#define O_WPK   516096     // convA weights [g2][kc8][tap9][nf2][lane][8] = 73728 f
#define O_A     589824     // A matrix bf16 [pix 8192][ck 2304] = 9437184 f
#define O_XT    10027008   // x NHWC bf16 [b][y][x][c] = 1048576 f
// P (convA fp16 partials) aliases the head of O_A (dead before gather writes A)
// total = 11,075,584 floats = 44.3 MB

__device__ __forceinline__ void gll16(const __hip_bfloat16* g, __hip_bfloat16* l) {
    __builtin_amdgcn_global_load_lds(
        (const __attribute__((address_space(1))) unsigned int*)g,
        (__attribute__((address_space(3))) unsigned int*)l, 16, 0, 0);
}

__device__ __forceinline__ short f2bf(float v) {
    __hip_bfloat16 h = __float2bfloat16(v);
    return *reinterpret_cast<short*>(&h);
}

__device__ __forceinline__ float bf2f(short s) {
    unsigned u = ((unsigned)(unsigned short)s) << 16;
    return __builtin_bit_cast(float, u);
}

// ---------------------------------------------------------------------------
// K0: pack weights (unchanged).
// ---------------------------------------------------------------------------
__global__ __launch_bounds__(256) void pack_kernel(
    const float* __restrict__ reg_w,
    const float* __restrict__ off_w,
    const float* __restrict__ mod_w,
    __hip_bfloat16* __restrict__ Wbf,
    __hip_bfloat16* __restrict__ Wpk)
{
    int idx = blockIdx.x * 256 + threadIdx.x;
    if (idx < CK * COo) {
        Wbf[idx] = __float2bfloat16(reg_w[idx]);
    }
    if (idx < 147456) {
        int g    = idx / 73728;
        int rem  = idx % 73728;
        int kc   = rem / 9216;
        int r2   = rem % 9216;
        int tap  = r2 / 1024;
        int r3   = r2 & 1023;
        int nf   = r3 >> 9;
        int r4   = r3 & 511;
        int lane = r4 >> 3;
        int j    = r4 & 7;
        int c    = kc * 32 + (lane >> 4) * 8 + j;
        int n    = nf * 16 + (lane & 15);
        float v = 0.f;
        if (g == 0) { if (n < 18) v = off_w[((size_t)n * CC + c) * 9 + tap]; }
        else        { if (n < 9)  v = mod_w[((size_t)n * CC + c) * 9 + tap]; }
        Wpk[idx] = __float2bfloat16(v);
    }
}

// ---------------------------------------------------------------------------
// K0b: x (NCHW fp32) -> xT (NHWC bf16). (unchanged)
// ---------------------------------------------------------------------------
__global__ __launch_bounds__(256) void transpose_kernel(
    const float* __restrict__ x,
    __hip_bfloat16* __restrict__ xT)
{
    int blk = blockIdx.x;            // ((b*64 + y)*8 + oc)
    int oc = blk & 7;
    int y  = (blk >> 3) & 63;
    int b  = blk >> 9;
    int t = threadIdx.x;
    int wo = t & 63;
    int cg = t >> 6;
    int c0 = oc * 32 + cg * 8;
    const float* src = x + ((size_t)(b * CC + c0) * HH + y) * WW + wo;
    shortx8 pk;
#pragma unroll
    for (int j = 0; j < 8; ++j) pk[j] = f2bf(src[(size_t)j * HWs]);
    *(shortx8*)(xT + ((size_t)b * 4096 + y * 64 + wo) * 256 + c0) = pk;
}

// ---------------------------------------------------------------------------
// K1: offset + modulator convs via MFMA (unchanged from R7).
// ---------------------------------------------------------------------------
__global__ __launch_bounds__(256) void convA_kernel(
    const float* __restrict__ x,
    const float* __restrict__ residual,
    const __hip_bfloat16* __restrict__ Wpk,
    _Float16* __restrict__ P)
{
    int blk = blockIdx.x;
    int rt = blk & 7;
    int kc = (blk >> 3) & 7;
    int g  = (blk >> 6) & 1;
    int b  = blk >> 7;
    int t = threadIdx.x;
    int lane = t & 63;
    int w = t >> 6;
    int ln = lane & 15;
    int quad = lane >> 4;

    __shared__ __hip_bfloat16 Xs[4 * 640 * 8];   // [chunk][row*64+col][8] (40 KB)
    __shared__ __hip_bfloat16 Wl[9216];          // weight slice (18 KB)

    const float* src = (g ? x : residual) + ((size_t)b * CC + kc * 32) * HWs;
    const __hip_bfloat16* wsrc = Wpk + (size_t)(g * 8 + kc) * 9216;

#pragma unroll
    for (int i = 0; i < 4; ++i) {
        int cid = i * 256 + t;
        gll16(wsrc + cid * 8, &Wl[cid * 8]);
    }
    if (t < 128) {
        int cid = 1024 + t;
        gll16(wsrc + cid * 8, &Wl[cid * 8]);
    }

    int col = t & 63;
    int q = t >> 6;
#pragma unroll
    for (int i = 0; i < 10; ++i) {
        int p = q * 10 + i;            // 0..39
        int row = p >> 2;              // 0..9
        int cgp = p & 3;               // c-chunk of 8
        int rimg = rt * 8 + row - 1;
        bool rv = (rimg >= 0) && (rimg < HH);
        const float* sp = src + (size_t)(cgp * 8) * HWs + rimg * WW + col;
        shortx8 pk;
#pragma unroll
        for (int jc = 0; jc < 8; ++jc)
            pk[jc] = f2bf(rv ? sp[(size_t)jc * HWs] : 0.f);
        *(shortx8*)&Xs[(cgp * 640 + row * 64 + col) * 8] = pk;
    }
    __syncthreads();

    floatx4 acc[8][2];
#pragma unroll
    for (int mf = 0; mf < 8; ++mf) {
        acc[mf][0] = (floatx4){0.f, 0.f, 0.f, 0.f};
        acc[mf][1] = (floatx4){0.f, 0.f, 0.f, 0.f};
    }

#pragma unroll
    for (int tap = 0; tap < 9; ++tap) {
        int ky = tap / 3;
        int kx = tap % 3;
        const __hip_bfloat16* wp = &Wl[((tap * 2) * 64 + lane) * 8];
        shortx8 b0 = *(const shortx8*)wp;
        shortx8 b1 = *(const shortx8*)(wp + 512);
#pragma unroll
        for (int mf = 0; mf < 8; ++mf) {
            int p = (w * 8 + mf) * 16 + ln;
            int row_local = p >> 6;
            int colp = p & 63;
            int colA = colp + kx - 1;
            bool cv = (colA >= 0) && (colA < WW);
            int colC = cv ? colA : 0;
            shortx8 afr = *(const shortx8*)
                &Xs[(quad * 640 + (row_local + ky) * 64 + colC) * 8];
            if (!cv) {
                shortx8 zf = {0,0,0,0,0,0,0,0};
                afr = zf;
            }
            acc[mf][0] = __builtin_amdgcn_mfma_f32_16x16x32_bf16(afr, b0, acc[mf][0], 0, 0, 0);
            acc[mf][1] = __builtin_amdgcn_mfma_f32_16x16x32_bf16(afr, b1, acc[mf][1], 0, 0, 0);
        }
    }

#pragma unroll
    for (int nf = 0; nf < 2; ++nf) {
        int n = nf * 16 + ln;
        bool valid = g ? (n < 9) : (n < 18);
        int n_eff = g ? (18 + n) : n;
        if (valid) {
#pragma unroll
            for (int mf = 0; mf < 8; ++mf) {
#pragma unroll
                for (int i2 = 0; i2 < 4; ++i2) {
                    int p = (w * 8 + mf) * 16 + quad * 4 + i2;
                    int pix = rt * 512 + p;
                    P[((size_t)(kc * 2 + b) * 4096 + pix) * 27 + n_eff] =
                        (_Float16)acc[mf][nf][i2];
                }
            }
        }
    }
}

// ---------------------------------------------------------------------------
// K1b: reduce 8 kc-partials + bias (+2*sigmoid) -> final off/mask. (unchanged)
// ---------------------------------------------------------------------------
__global__ __launch_bounds__(256) void reduce_kernel(
    const _Float16* __restrict__ P,
    const float* __restrict__ off_b,
    const float* __restrict__ mod_b,
    float* __restrict__ off_out,
    float* __restrict__ mask_out)
{
    int id = blockIdx.x * 256 + threadIdx.x;
    if (id >= 2 * 4096 * 27) return;
    int n = id % 27;
    int pb = id / 27;
    int pix = pb & 4095;
    int b = pb >> 12;
    float s = 0.f;
#pragma unroll
    for (int kcc = 0; kcc < 8; ++kcc)
        s += (float)P[((size_t)(kcc * 2 + b) * 4096 + pix) * 27 + n];
    if (n < 18) {
        off_out[((size_t)b * 18 + n) * 4096 + pix] = s + off_b[n];
    } else {
        float z = s + mod_b[n - 18];
        mask_out[((size_t)b * 9 + (n - 18)) * 4096 + pix] = 2.f / (1.f + __expf(-z));
    }
}

// ---------------------------------------------------------------------------
// K2: deformable gather -> bf16 A [pix][ck]. (unchanged from R7)
// ---------------------------------------------------------------------------
__global__ __launch_bounds__(256) void gather_kernel(
    const __hip_bfloat16* __restrict__ xT,
    const float* __restrict__ off,
    const float* __restrict__ mask,
    __hip_bfloat16* __restrict__ A)
{
    int blk = blockIdx.x;            // ((b*64 + ho)*8 + cc)
    int cc = blk & 7;
    int ho = (blk >> 3) & 63;
    int b  = blk >> 9;
    int t  = threadIdx.x;
    int wo = t & 63;
    int cg = t >> 6;

    __shared__ int   s_idx[4][K2][64];
    __shared__ float s_w  [4][K2][64];

    for (int u = t; u < K2 * 64; u += 256) {
        int k = u >> 6;
        int wv = u & 63;
        float dy = off[((((size_t)b * 18 + 2 * k    ) * HH + ho) << 6) + wv];
        float dx = off[((((size_t)b * 18 + 2 * k + 1) * HH + ho) << 6) + wv];
        float m  = mask[((((size_t)b * 9 + k) * HH + ho) << 6) + wv];
        float py = (float)(ho - 1 + k / 3) + dy;
        float px = (float)(wv - 1 + k % 3) + dx;
        float y0f = floorf(py), x0f = floorf(px);
        float wy1 = py - y0f, wx1 = px - x0f;
        float wy0 = 1.f - wy1, wx0 = 1.f - wx1;
        int y0 = (int)y0f, x0 = (int)x0f;
#pragma unroll
        for (int j = 0; j < 4; ++j) {
            int yy = y0 + (j >> 1);
            int xx = x0 + (j & 1);
            float wj = ((j == 0) ? wy0 * wx0 :
                        (j == 1) ? wy0 * wx1 :
                        (j == 2) ? wy1 * wx0 : wy1 * wx1) * m;
            bool valid = (yy >= 0) && (yy < HH) && (xx >= 0) && (xx < WW);
            s_idx[j][k][wv] = valid ? (yy * WW + xx) : 0;
            s_w  [j][k][wv] = valid ? wj : 0.f;
        }
    }
    __syncthreads();

    const __hip_bfloat16* xb = xT + (size_t)b * 4096 * 256 + cc * 32 + cg * 8;

    shortx8 outv[9];
#pragma unroll
    for (int k = 0; k < K2; ++k) {
        int   i0 = s_idx[0][k][wo], i1 = s_idx[1][k][wo];
        int   i2 = s_idx[2][k][wo], i3 = s_idx[3][k][wo];
        float w0 = s_w[0][k][wo], w1 = s_w[1][k][wo];
        float w2 = s_w[2][k][wo], w3 = s_w[3][k][wo];
        shortx8 c0 = *(const shortx8*)(xb + (size_t)i0 * 256);
        shortx8 c1 = *(const shortx8*)(xb + (size_t)i1 * 256);
        shortx8 c2 = *(const shortx8*)(xb + (size_t)i2 * 256);
        shortx8 c3 = *(const shortx8*)(xb + (size_t)i3 * 256);
#pragma unroll
        for (int j = 0; j < 8; ++j) {
            float v = w0 * bf2f(c0[j]) + w1 * bf2f(c1[j])
                    + w2 * bf2f(c2[j]) + w3 * bf2f(c3[j]);
            int idx = j * 9 + k;
            outv[idx >> 3][idx & 7] = f2bf(v);
        }
    }

    __hip_bfloat16* arow = A + (size_t)((b * 64 + ho) * 64 + wo) * CK
                             + cc * 288 + cg * 72;
#pragma unroll
    for (int m = 0; m < 9; ++m)
        *(shortx8*)(arow + m * 8) = outv[m];
}

// ---------------------------------------------------------------------------
// K3: bf16 MFMA GEMM  C[8192][256] = A[8192][2304] x Wbf^T, out NCHW.
// grid = 256 (mt 128 x nt 2), tile 64M x 128N, BK=64, double-buffered DMA.
// Swizzle: global chunk = sub ^ (row&7); read slot = q ^ (ln&7) -> all 32
// banks covered exactly 8x per wave-b128 (structural min, zero conflicts).
// No K-split, no atomics. Per-wave 32Mx64N (acc 2x4), per-wave LDS epilogue.
// ---------------------------------------------------------------------------
__global__ __launch_bounds__(256) void gemm_kernel(
    const __hip_bfloat16* __restrict__ A,
    const __hip_bfloat16* __restrict__ Wbf,
    float* __restrict__ out)
{
    int blk = blockIdx.x;
    int nt = blk & 1;
    int mt = blk >> 1;              // 0..127
    int t  = threadIdx.x;
    int lane = t & 63;
    int w    = t >> 6;
    int quad = lane >> 4;
    int ln   = lane & 15;
    int wm = w & 1;                 // M half (32 rows)
    int wn = w >> 1;                // N half (64 cols)

    __shared__ __hip_bfloat16 As[2][64 * 64];    // 2 x 8 KB
    __shared__ __hip_bfloat16 Bs[2][128 * 64];   // 2 x 16 KB
    __shared__ float s_out[4][16 * 40];          // per-wave epilogue (10 KB)

    int lr8 = lane >> 3;            // 0..7 (staging row within wave's 8)
    int sub = lane & 7;             // 16B slot within 128B row
    int chk = sub ^ lr8;            // global k-chunk this lane fetches

    // global row bases: row = h*32 + w*8 + lr8   (row&7 == lr8)
    const __hip_bfloat16* gA = A + (size_t)(mt * 64 + w * 8 + lr8) * CK + chk * 8;
    const __hip_bfloat16* gB = Wbf + (size_t)(nt * 128 + w * 8 + lr8) * CK + chk * 8;
    // wave-uniform LDS bases (HW adds lane*16B)
    int lofA = w * 512;             // elements
    int lofB = w * 512;

    floatx4 acc[2][4];
#pragma unroll
    for (int mf = 0; mf < 2; ++mf)
#pragma unroll
        for (int nf = 0; nf < 4; ++nf) acc[mf][nf] = (floatx4){0.f, 0.f, 0.f, 0.f};

    // prologue: stage kt=0 into buffer 0
#pragma unroll
    for (int h = 0; h < 2; ++h)
        gll16(gA + (size_t)(h * 32) * CK, &As[0][lofA + h * 2048]);
#pragma unroll
    for (int h = 0; h < 4; ++h)
        gll16(gB + (size_t)(h * 32) * CK, &Bs[0][lofB + h * 2048]);

    int swz = ln & 7;               // read-slot XOR key

    for (int kt = 0; kt < 36; ++kt) {
        int cur = kt & 1;
        int nxt = cur ^ 1;
        __syncthreads();                      // buf[cur] staging complete
        if (kt + 1 < 36) {
            int ko = (kt + 1) * 64;
#pragma unroll
            for (int h = 0; h < 2; ++h)
                gll16(gA + (size_t)(h * 32) * CK + ko, &As[nxt][lofA + h * 2048]);
#pragma unroll
            for (int h = 0; h < 4; ++h)
                gll16(gB + (size_t)(h * 32) * CK + ko, &Bs[nxt][lofB + h * 2048]);
        }
#pragma unroll
        for (int kh = 0; kh < 2; ++kh) {
            int slot = ((kh * 4 + quad) ^ swz) * 8;
            shortx8 af[2], bf[4];
#pragma unroll
            for (int mf = 0; mf < 2; ++mf)
                af[mf] = *(const shortx8*)
                    &As[cur][(wm * 32 + mf * 16 + ln) * 64 + slot];
#pragma unroll
            for (int nf = 0; nf < 4; ++nf)
                bf[nf] = *(const shortx8*)
                    &Bs[cur][(wn * 64 + nf * 16 + ln) * 64 + slot];
#pragma unroll
            for (int mf = 0; mf < 2; ++mf)
#pragma unroll
                for (int nf = 0; nf < 4; ++nf)
                    acc[mf][nf] = __builtin_amdgcn_mfma_f32_16x16x32_bf16(
                        af[mf], bf[nf], acc[mf][nf], 0, 0, 0);
        }
    }

    // ---- epilogue: per-wave LDS transpose (pitch 40), coalesced stores ----
    int bb = mt >> 6;
    int hw0 = (mt & 63) * 64 + wm * 32;
    float* sw = &s_out[w][0];
    int co_l = lane >> 2;
    int seg  = lane & 3;
#pragma unroll
    for (int nf = 0; nf < 4; ++nf) {
        *(floatx4*)&sw[ln * 40 + quad * 4]      = acc[0][nf];
        *(floatx4*)&sw[ln * 40 + 16 + quad * 4] = acc[1][nf];
        // wave-internal RAW: compiler inserts lgkmcnt wait (same LDS array)
        floatx4 v0 = *(const floatx4*)&sw[co_l * 40 + seg * 4];
        floatx4 v1 = *(const floatx4*)&sw[co_l * 40 + 16 + seg * 4];
        int co = nt * 128 + wn * 64 + nf * 16 + co_l;
        float* orow = out + ((size_t)(bb * COo + co) << 12) + hw0;
        *(floatx4*)&orow[seg * 4]      = v0;
        *(floatx4*)&orow[16 + seg * 4] = v1;
    }
}

// ---------------------------------------------------------------------------
extern "C" void kernel_launch(void* const* d_in, const int* in_sizes, int n_in,
                              void* d_out, int out_size, void* d_ws, size_t ws_size,
                              hipStream_t stream)
{
    const float* x     = (const float*)d_in[0];
    const float* resid = (const float*)d_in[1];
    const float* off_w = (const float*)d_in[2];
    const float* off_b = (const float*)d_in[3];
    const float* mod_w = (const float*)d_in[4];
    const float* mod_b = (const float*)d_in[5];
    const float* reg_w = (const float*)d_in[6];
    float* out = (float*)d_out;

    float* ws = (float*)d_ws;
    float* off_buf   = ws + O_OFF;
    float* mask_buf  = ws + O_MASK;
    __hip_bfloat16* Wbf  = (__hip_bfloat16*)(ws + O_WBF);
    __hip_bfloat16* Wpk  = (__hip_bfloat16*)(ws + O_WPK);
    __hip_bfloat16* Abuf = (__hip_bfloat16*)(ws + O_A);
    __hip_bfloat16* xT   = (__hip_bfloat16*)(ws + O_XT);
    _Float16* Pbuf       = (_Float16*)(ws + O_A);   // aliases A head

    pack_kernel<<<(CK * COo + 255) / 256, 256, 0, stream>>>(reg_w, off_w, mod_w, Wbf, Wpk);

    transpose_kernel<<<BB * HH * 8, 256, 0, stream>>>(x, xT);

    convA_kernel<<<256, 256, 0, stream>>>(x, resid, Wpk, Pbuf);

    reduce_kernel<<<864, 256, 0, stream>>>(Pbuf, off_b, mod_b, off_buf, mask_buf);

    gather_kernel<<<BB * HH * 8, 256, 0, stream>>>(xT, off_buf, mask_buf, Abuf);

    gemm_kernel<<<256, 256, 0, stream>>>(Abuf, Wbf, out);
}